// Round 1
// baseline (274.177 us; speedup 1.0000x reference)
//
#include <hip/hip_runtime.h>
#include <hip/hip_bf16.h>
#include <stdint.h>

#define D 128
#define CAP 48        // fixed per-node slot capacity (Poisson(12.8): P(deg>48)~1e-13)
#define OVFCAP 65536
#define NPB 32        // nodes per block in gg_kernel (X tile = 32x1024 bf16 = 64 KB LDS)

using bf16x8 = __attribute__((ext_vector_type(8))) short;
using f32x4  = __attribute__((ext_vector_type(4))) float;

__device__ __forceinline__ unsigned short f2bf(float f) {
    unsigned u = __float_as_uint(f);
    u = (u + 0x7fffu + ((u >> 16) & 1u)) >> 16;   // RNE
    return (unsigned short)u;
}
__device__ __forceinline__ float bf2f(unsigned short h) {
    return __uint_as_float(((unsigned)h) << 16);
}

__device__ __forceinline__ bf16x8 cvt8(float4 a, float4 b) {
    union { bf16x8 v; __hip_bfloat162 h[4]; } u;
    u.h[0] = __float22bfloat162_rn(make_float2(a.x, a.y));
    u.h[1] = __float22bfloat162_rn(make_float2(a.z, a.w));
    u.h[2] = __float22bfloat162_rn(make_float2(b.x, b.y));
    u.h[3] = __float22bfloat162_rn(make_float2(b.z, b.w));
    return u.v;
}

// ---------- zero deg/ovf counters ----------
__global__ __launch_bounds__(256) void k_zero(int* __restrict__ deg, int N)
{
    int i = blockIdx.x * 256 + threadIdx.x;
    if (i <= N) deg[i] = 0;
}

// ---------- prep + count fused (Bresenham-interleaved) ----------
// featb = bf16(feat); Wt[r][c][k] = bf16(W[r][k][c]); count: per-edge
// ord = atomicAdd(deg[dst]); slots[dst*CAP+ord] = (src<<8)|et  (src byte
// offset into featb = key & ~0xFF since a row is 256 B).
__global__ __launch_bounds__(256) void prepcnt_kernel(
    const float* __restrict__ feat, unsigned short* __restrict__ featb,
    const float* __restrict__ W, unsigned short* __restrict__ Wt,
    const int* __restrict__ et, const int* __restrict__ src,
    const int* __restrict__ dst,
    int* __restrict__ deg, unsigned int* __restrict__ slots,
    int* __restrict__ ovf,
    int N, int E, int fcTotal, int wtTotal, int fwBlocks, int cntBlocks)
{
    const int b = blockIdx.x;
    const long long total = (long long)fwBlocks + cntBlocks;
    long long cb = ((long long)b * cntBlocks) / total;
    bool isCount = (((long long)(b + 1) * cntBlocks) / total) > cb;

    if (isCount) {
        int e = (int)cb * 256 + threadIdx.x;
        if (e < E) {
            int d = dst[e];
            unsigned key = ((unsigned)src[e] << 8) | (unsigned)et[e];
            int ord = atomicAdd(&deg[d], 1);
            if (ord < CAP) {
                slots[(size_t)d * CAP + ord] = key;
            } else {
                int o = atomicAdd(&deg[N], 1);
                if (o < OVFCAP) ovf[o] = e;
            }
        }
        return;
    }

    int idx = (int)(b - cb);
    int fcBlocks = (fcTotal + 255) >> 8;
    if (idx < fcBlocks) {
        int i = idx * 256 + threadIdx.x;
        if (i < fcTotal) {
            const float4* p = (const float4*)feat + (size_t)i * 2;
            *(bf16x8*)(featb + (size_t)i * 8) = cvt8(p[0], p[1]);
        }
    } else {
        int i2 = (idx - fcBlocks) * 256 + threadIdx.x;
        if (i2 < wtTotal) {
            int r = i2 >> 14;
            int rem = i2 & 16383;
            int k = rem >> 7, c = rem & 127;
            Wt[(r << 14) + (c << 7) + k] = f2bf(W[i2]);
        }
    }
}

// ---------- gather + aggregate + GEMM fused ----------
// Per block: 32 nodes. Phase 1 (per wave, 8 nodes each): gather bf16 feat
// rows of incoming edges (64 lanes x 4 B = one 256 B coalesced load/edge),
// accumulate per-rel sums in fp32 regs (rel is wave-uniform -> scalar
// switch), write X[slot][k=rel*128+ch] bf16 to LDS with fused3's 16B-chunk
// XOR swizzle. Phase 2: OUT[32 x 128] = X[32 x 1024] @ Wcat[1024 x 128]
// via mfma_16x16x32_bf16; A = Wt rows (global, L2-resident), B = X (LDS,
// conflict-free ds_read_b128). Epilogue: out = feat + acc (fp32 residual).
__global__ __launch_bounds__(256, 2) void gg_kernel(
    const unsigned short* __restrict__ featb, const unsigned short* __restrict__ Wt,
    const unsigned int* __restrict__ slots, const int* __restrict__ deg,
    const float* __restrict__ feat, float* __restrict__ out, int N)
{
    __shared__ __align__(16) unsigned short sX[NPB * 1024];   // 64 KB
    const int tid  = threadIdx.x;
    const int wave = tid >> 6, lane = tid & 63;
    const int q    = lane >> 4, mlo = lane & 15;
    const int nbase = blockIdx.x * NPB;
    const int gbase = nbase + wave * 8;

    // deg for this wave's 8 nodes (lanes 0..7 hold them)
    int dgl;
    { int nn = gbase + (lane & 7); dgl = (nn < N) ? deg[nn < N ? nn : 0] : 0; }

    const int slotsel = lane < CAP ? lane : CAP - 1;
    unsigned kv_cur;
    { int n0 = gbase < N ? gbase : 0; kv_cur = slots[(size_t)n0 * CAP + slotsel]; }

    for (int i = 0; i < 8; ++i) {
        const int node = gbase + i;
        int dg = __builtin_amdgcn_readlane(dgl, i);
        int capped = (node < N) ? (dg < CAP ? dg : CAP) : 0;
        unsigned kv = kv_cur;
        if (i < 7) {                                   // prefetch next node's keys
            int n1 = gbase + i + 1; if (n1 >= N) n1 = 0;
            kv_cur = slots[(size_t)n1 * CAP + slotsel];
        }

        float acc[16];
        #pragma unroll
        for (int r = 0; r < 16; ++r) acc[r] = 0.f;

        for (int done = 0; done < capped; done += 16) {
            int bc = capped - done; if (bc > 16) bc = 16;
            unsigned a[16]; unsigned kk[16];
            #pragma unroll
            for (int u = 0; u < 16; ++u) if (u < bc) {
                kk[u] = __builtin_amdgcn_readlane(kv, done + u);   // scalar key
                a[u] = *(const unsigned*)((const char*)featb
                         + (size_t)(kk[u] & 0xFFFFFF00u) + (lane << 2));
            }
            #pragma unroll
            for (int u = 0; u < 16; ++u) if (u < bc) {
                int r = (int)(kk[u] & 0xFFu);                      // wave-uniform
                float lo = __uint_as_float(a[u] << 16);
                float hi = __uint_as_float(a[u] & 0xffff0000u);
                switch (r) {
                    case 0: acc[0]  += lo; acc[1]  += hi; break;
                    case 1: acc[2]  += lo; acc[3]  += hi; break;
                    case 2: acc[4]  += lo; acc[5]  += hi; break;
                    case 3: acc[6]  += lo; acc[7]  += hi; break;
                    case 4: acc[8]  += lo; acc[9]  += hi; break;
                    case 5: acc[10] += lo; acc[11] += hi; break;
                    case 6: acc[12] += lo; acc[13] += hi; break;
                    default: acc[14] += lo; acc[15] += hi; break;
                }
            }
        }

        // write X row: element k = r*128 + 2*lane (+1); 16B-chunk XOR swizzle
        const int slot = wave * 8 + i;
        char* xb = (char*)sX + (size_t)slot * 2048;
        const int sw = slot & 15;
        #pragma unroll
        for (int r = 0; r < 8; ++r) {
            __hip_bfloat162 pv = __float22bfloat162_rn(make_float2(acc[2*r], acc[2*r+1]));
            int chunk = (r << 4) + (lane >> 2);
            *(unsigned*)(xb + (((chunk ^ sw) << 4) | ((lane & 3) << 2))) = *(unsigned*)&pv;
        }
    }
    __syncthreads();

    // ---- MFMA phase: wave owns 32 output channels x all 32 nodes ----
    const int cbase = wave * 32;
    f32x4 accm[2][2];
    #pragma unroll
    for (int mt = 0; mt < 2; ++mt)
        #pragma unroll
        for (int g = 0; g < 2; ++g)
            accm[mt][g] = (f32x4){0.f, 0.f, 0.f, 0.f};

    const char* xr = (const char*)sX;
    #pragma unroll 4
    for (int ks = 0; ks < 32; ++ks) {
        const int r = ks >> 2;
        const int joff = ((ks & 3) << 5) + (q << 3);
        bf16x8 af[2], bfv[2];
        #pragma unroll
        for (int mt = 0; mt < 2; ++mt) {
            int c = cbase + (mt << 4) + mlo;
            af[mt] = *(const bf16x8*)(Wt + ((size_t)r << 14) + (c << 7) + joff);
        }
        #pragma unroll
        for (int g = 0; g < 2; ++g) {
            int slot = (g << 4) + mlo;
            int chunk = (ks << 2) + q;
            bfv[g] = *(const bf16x8*)(xr + (size_t)slot * 2048
                        + (((chunk ^ (slot & 15)) << 4)));
        }
        #pragma unroll
        for (int mt = 0; mt < 2; ++mt)
            #pragma unroll
            for (int g = 0; g < 2; ++g)
                accm[mt][g] = __builtin_amdgcn_mfma_f32_16x16x32_bf16(
                    af[mt], bfv[g], accm[mt][g], 0, 0, 0);
    }

    // epilogue: out = feat + acc  (D row = q*4+reg -> channel, col = mlo -> node)
    #pragma unroll
    for (int g = 0; g < 2; ++g) {
        int node = nbase + (g << 4) + mlo;
        if (node < N) {
            #pragma unroll
            for (int mt = 0; mt < 2; ++mt) {
                int c = cbase + (mt << 4) + (q << 2);
                float4 fv = *(const float4*)(feat + (size_t)node * D + c);
                f32x4 a = accm[mt][g];
                float4 o = {fv.x + a[0], fv.y + a[1], fv.z + a[2], fv.w + a[3]};
                *(float4*)(out + (size_t)node * D + c) = o;
            }
        }
    }
}

// ---------- overflow: direct fp32 matvec + atomicAdd (normally 0 work) ----------
__global__ __launch_bounds__(256) void k_ovf2(
    const float* __restrict__ feat, const float* __restrict__ W,
    const int* __restrict__ ovf, const int* __restrict__ deg,
    const int* __restrict__ dst, const int* __restrict__ et,
    const int* __restrict__ src, float* __restrict__ out, int N)
{
    int cnt = deg[N];
    if (cnt > OVFCAP) cnt = OVFCAP;
    int wid = (blockIdx.x * 256 + threadIdx.x) >> 6;
    int nw = (gridDim.x * 256) >> 6;
    int lane = threadIdx.x & 63;
    for (int i = wid; i < cnt; i += nw) {
        int e = ovf[i];
        int d = dst[e], r = et[e], s = src[e];
        const float* x = feat + (size_t)s * D;
        const float* Wr = W + (size_t)r * D * D;
        float a0 = 0.f, a1 = 0.f;
        #pragma unroll 8
        for (int k = 0; k < D; ++k) {
            float xv = x[k];
            a0 += xv * Wr[(size_t)k * D + 2 * lane];
            a1 += xv * Wr[(size_t)k * D + 2 * lane + 1];
        }
        atomicAdd(out + (size_t)d * D + 2 * lane,     a0);
        atomicAdd(out + (size_t)d * D + 2 * lane + 1, a1);
    }
}

// ---------- fallbacks ----------
__global__ __launch_bounds__(256) void init_kernel(
    const float* __restrict__ feat, float* __restrict__ out, int n4)
{
    int i = blockIdx.x * 256 + threadIdx.x;
    if (i < n4) ((float4*)out)[i] = ((const float4*)feat)[i];
}

__global__ __launch_bounds__(128) void edge_matvec_kernel(
    const float* __restrict__ feat, const float* __restrict__ W,
    const int* __restrict__ et, const int* __restrict__ src,
    const int* __restrict__ dst, float* __restrict__ out, int E)
{
    __shared__ float xs[D];
    int e = blockIdx.x;
    int c = threadIdx.x;
    int s = src[e], r = et[e], d = dst[e];
    xs[c] = feat[(size_t)s * D + c];
    __syncthreads();
    const float* Wr = W + (size_t)r * D * D;
    float acc = 0.f;
    #pragma unroll 8
    for (int k = 0; k < D; ++k) acc += xs[k] * Wr[(size_t)k * D + c];
    atomicAdd(out + (size_t)d * D + c, acc);
}

static inline size_t al256(size_t x) { return (x + 255) & ~(size_t)255; }

extern "C" void kernel_launch(void* const* d_in, const int* in_sizes, int n_in,
                              void* d_out, int out_size, void* d_ws, size_t ws_size,
                              hipStream_t stream) {
    const float* feat = (const float*)d_in[0];
    const float* W    = (const float*)d_in[1];
    const int*   et   = (const int*)d_in[2];
    const int*   src  = (const int*)d_in[3];
    const int*   dst  = (const int*)d_in[4];
    float* out = (float*)d_out;

    const int N = in_sizes[0] / D;
    const int R = in_sizes[1] / (D * D);
    const int E = in_sizes[2];

    size_t wtB  = al256((size_t)R * D * D * sizeof(unsigned short));
    size_t degB = al256((size_t)(N + 1) * sizeof(int));
    size_t sltB = al256((size_t)N * CAP * sizeof(unsigned int));
    size_t ovfB = al256((size_t)OVFCAP * sizeof(int));
    size_t fbB  = al256((size_t)N * D * sizeof(unsigned short));
    size_t need = wtB + degB + sltB + ovfB + fbB;

    // key packing needs src < 2^24 and et < 256
    const bool packable = (N <= (1 << 24)) && (R <= 256);

    if (ws_size >= need && packable) {
        char* p = (char*)d_ws;
        unsigned short* Wt     = (unsigned short*)p;           p += wtB;
        int*            deg    = (int*)p;                      p += degB;
        unsigned int*   slots  = (unsigned int*)p;             p += sltB;
        int*            ovf    = (int*)p;                      p += ovfB;
        unsigned short* featb  = (unsigned short*)p;

        int wtTotal = R * D * D;
        int fcTotal = (N * D) / 8;
        int zB  = (N + 1 + 255) / 256;
        int fcB = (fcTotal + 255) / 256;
        int wtBk = (wtTotal + 255) / 256;
        int cntB = (E + 255) / 256;
        int fwB = fcB + wtBk;

        k_zero<<<zB, 256, 0, stream>>>(deg, N);

        prepcnt_kernel<<<fwB + cntB, 256, 0, stream>>>(
            feat, featb, W, Wt, et, src, dst, deg, slots, ovf,
            N, E, fcTotal, wtTotal, fwB, cntB);

        int ggB = (N + NPB - 1) / NPB;
        gg_kernel<<<ggB, 256, 0, stream>>>(featb, Wt, slots, deg, feat, out, N);

        k_ovf2<<<16, 256, 0, stream>>>(feat, W, ovf, deg, dst, et, src, out, N);
    } else {
        int n4 = (N * D) / 4;
        init_kernel<<<(n4 + 255) / 256, 256, 0, stream>>>(feat, out, n4);
        edge_matvec_kernel<<<E, 128, 0, stream>>>(feat, W, et, src, dst, out, E);
    }
}